// Round 5
// baseline (958.516 us; speedup 1.0000x reference)
//
#include <hip/hip_runtime.h>
#include <stdint.h>
#include <stddef.h>

// S=8192, D=1024 causal attention + QKV proj.
// cast->bf16, fused QKV MFMA GEMM (async LDS staging, writes Q/K blocked
// MFMA-fragment layout), V transpose (blocked B-frag), flash attention
// (Br=32, Bc=256, 8 waves, pair-balanced + key-parity split-2, 2-pass
// phase C for small LDS, 2 blocks/CU), merge kernel.

#define SEQ   8192
#define DIM   1024

typedef __bf16 bf16x8 __attribute__((ext_vector_type(8)));
typedef float  f32x4  __attribute__((ext_vector_type(4)));
typedef uint16_t u16x8 __attribute__((ext_vector_type(8)));

#define MFMA16(a, b, c) __builtin_amdgcn_mfma_f32_16x16x32_bf16((a), (b), (c), 0, 0, 0)

__device__ __forceinline__ uint16_t f2bf(float f) {
  uint32_t u = __builtin_bit_cast(uint32_t, f);
  return (uint16_t)((u + 0x7fffu + ((u >> 16) & 1u)) >> 16);
}
__device__ __forceinline__ float bf2f(uint16_t h) {
  uint32_t u = ((uint32_t)h) << 16;
  return __builtin_bit_cast(float, u);
}

typedef const __attribute__((address_space(1))) uint32_t* gas_t;
typedef __attribute__((address_space(3))) uint32_t* las_t;
__device__ __forceinline__ void async16(const void* g, void* l) {
  // 16B per lane; LDS dest = wave-uniform base + lane*16
  __builtin_amdgcn_global_load_lds((gas_t)g, (las_t)l, 16, 0, 0);
}

// ---------------------------------------------------------------- cast kernel
__global__ __launch_bounds__(256) void cast_f32_bf16(const float* __restrict__ src,
                                                     uint16_t* __restrict__ dst, int n) {
  int i = (blockIdx.x * 256 + threadIdx.x) * 4;
  if (i + 3 < n) {
    float4 v = *(const float4*)(src + i);
    ushort4 o;
    o.x = f2bf(v.x); o.y = f2bf(v.y); o.z = f2bf(v.z); o.w = f2bf(v.w);
    *(ushort4*)(dst + i) = o;
  }
}

// ------------------------------------------------------------- QKV GEMM
// m97-style: global_load_lds width-16 staging, unpadded LDS with XOR-16B-group
// source swizzle (frag reads 2-way aliased = free). 128x128 tile, BK=64.
// Q,K written in blocked A/B-frag layout; V row-major (transposed next).
__global__ __launch_bounds__(256) void qkv_gemm(const uint16_t* __restrict__ A,
                                                const uint16_t* __restrict__ B,
                                                uint16_t* __restrict__ Qblk,
                                                uint16_t* __restrict__ Kblk,
                                                uint16_t* __restrict__ Vb) {
  __shared__ __align__(16) uint16_t As[128 * 64];
  __shared__ __align__(16) uint16_t Bs[128 * 64];
  const int t    = threadIdx.x;
  const int w    = t >> 6;
  const int lane = t & 63;
  const int lm   = lane & 15;
  const int qd   = lane >> 4;
  const int wrow = (w >> 1) * 64;
  const int wcol = (w & 1) * 64;
  const int rowbase = blockIdx.y * 128;
  const int colbase = blockIdx.x * 128;

  const int lrow = lane >> 3;                    // row within 8-row slab
  const int lgrp = (lane & 7) ^ (lrow & 7);      // XOR-swizzled source 16B group

  f32x4 acc[4][4] = {};

  for (int kb = 0; kb < DIM; kb += 64) {
    __syncthreads();
#pragma unroll
    for (int rep = 0; rep < 4; ++rep) {
      int r0 = rep * 32 + w * 8;                 // 8-row slab base (8-aligned)
      async16(A + (size_t)(rowbase + r0 + lrow) * DIM + kb + lgrp * 8, As + r0 * 64);
      async16(B + (size_t)(colbase + r0 + lrow) * DIM + kb + lgrp * 8, Bs + r0 * 64);
    }
    __syncthreads();
#pragma unroll
    for (int kc = 0; kc < 2; ++kc) {
      bf16x8 af[4], bfr[4];
#pragma unroll
      for (int mt = 0; mt < 4; ++mt) {
        int r = wrow + mt * 16 + lm;
        af[mt] = *(const bf16x8*)(As + r * 64 + (((kc * 4 + qd) ^ (lm & 7)) * 8));
      }
#pragma unroll
      for (int nt = 0; nt < 4; ++nt) {
        int r = wcol + nt * 16 + lm;
        bfr[nt] = *(const bf16x8*)(Bs + r * 64 + (((kc * 4 + qd) ^ (lm & 7)) * 8));
      }
#pragma unroll
      for (int mt = 0; mt < 4; ++mt)
#pragma unroll
        for (int nt = 0; nt < 4; ++nt)
          acc[mt][nt] = MFMA16(af[mt], bfr[nt], acc[mt][nt]);
    }
  }

#pragma unroll
  for (int mt = 0; mt < 4; ++mt)
#pragma unroll
    for (int nt = 0; nt < 4; ++nt)
#pragma unroll
      for (int r = 0; r < 4; ++r) {
        int m = rowbase + wrow + mt * 16 + qd * 4 + r;
        int n = colbase + wcol + nt * 16 + lm;
        uint16_t v = f2bf(acc[mt][nt][r]);
        int nn = n & 1023;
        if (n < 2048) {
          size_t off = (((size_t)(m >> 4) * 32 + (nn >> 5)) * 64 +
                        ((nn >> 3) & 3) * 16 + (m & 15)) * 8 + (nn & 7);
          if (n < 1024) Qblk[off] = v; else Kblk[off] = v;
        } else {
          Vb[(size_t)m * DIM + nn] = v;
        }
      }
}

// ------------------------------------------------------------ V transpose
__global__ __launch_bounds__(256) void transpose_v(const uint16_t* __restrict__ Vb,
                                                   uint16_t* __restrict__ Vblk) {
  __shared__ __align__(16) uint16_t tile[64][72];
  const int t  = threadIdx.x;
  const int mb = blockIdx.x * 64;   // key base
  const int db = blockIdx.y * 64;   // d base
#pragma unroll
  for (int rep = 0; rep < 2; ++rep) {
    int i = rep * 256 + t;
    int r = i >> 3, c = (i & 7) * 8;
    *(uint4*)(&tile[r][c]) = *(const uint4*)(Vb + (size_t)(mb + r) * DIM + db + c);
  }
  __syncthreads();
#pragma unroll
  for (int rep = 0; rep < 2; ++rep) {
    int i = rep * 256 + t;
    int d = i >> 3, mq = (i & 7) * 8;
    u16x8 v;
#pragma unroll
    for (int u = 0; u < 8; ++u) v[u] = tile[mq + u][d];
    int dg = db + d, kg = mb + mq;
    size_t off = (((size_t)(dg >> 4) * 256 + (kg >> 5)) * 64 +
                  ((kg >> 3) & 3) * 16 + (dg & 15)) * 8;
    *(u16x8*)(Vblk + off) = v;
  }
}

// ------------------------------------------------------------ flash attention
// Br=32 rows, Bc=256 keys/iter, 8 waves (512 thr), forced <=128 regs so
// 2 blocks/CU. grid=256: pair p=b>>1 (halves tt=p, 255-p), parity par=b&1.
// Phase A: wave w owns S cols [32w,+32); Q from LDS (blocked), K global
// (blocked, lane-contiguous). Softmax in registers. Phase C split into two
// 128-key passes through an 8KB Pb buffer (pv held packed in regs between
// passes); wave w owns d-slice [128w,+128); V global (blocked).
__global__ __launch_bounds__(512, 4) void attn_kernel(const uint16_t* __restrict__ Qblk,
                                                      const uint16_t* __restrict__ Kblk,
                                                      const uint16_t* __restrict__ Vblk,
                                                      uint16_t* __restrict__ P0,
                                                      uint16_t* __restrict__ P1,
                                                      float* __restrict__ Mm,
                                                      float* __restrict__ Ll) {
  __shared__ __align__(16) uint16_t Qs[32768];   // 64KB blocked Q tile
  __shared__ __align__(16) uint16_t Pb[4096];    // 8KB: [mt(2)][kcblk(4)][lane(64)][8]
  __shared__ float stats[32][8];                 // smax during loop; lsum in epilogue
  __shared__ float mrow[32];

  const int t    = threadIdx.x;
  const int w    = t >> 6;
  const int lane = t & 63;
  const int lm   = lane & 15;
  const int qd   = lane >> 4;
  const int wp   = w >> 2;   // which C-pass this wave's P-cols belong to
  const int wk   = w & 3;    // k32-block within the pass
  const int par  = blockIdx.x & 1;
  const int p    = blockIdx.x >> 1;
  const float c1 = 0.045084220027780106f;  // log2(e)/sqrt(1024)

#pragma unroll 1
  for (int half = 0; half < 2; ++half) {
    const int tt   = half ? 255 - p : p;
    const int row0 = tt * 32;
    const int jn   = (tt >> 3) + 1;

    __syncthreads();  // previous half done with Qs
#pragma unroll
    for (int i = 0; i < 8; ++i)
      async16(Qblk + ((size_t)(tt * 64 + w * 8 + i)) * 512 + lane * 8,
              Qs + (w * 8 + i) * 512);
    __syncthreads();  // drain DMA

    float m_run[2][4], l_run[2][4];
#pragma unroll
    for (int mt = 0; mt < 2; ++mt)
#pragma unroll
      for (int r = 0; r < 4; ++r) { m_run[mt][r] = -1e30f; l_run[mt][r] = 0.0f; }
    f32x4 o_acc[2][8] = {};

#pragma unroll 1
    for (int jg = par; jg < jn; jg += 2) {
      // ---- Phase A: sacc = Q K^T (32 rows x 32 cols this wave) -----------
      f32x4 sacc[2][2] = {};
      const uint16_t* kbp = Kblk + ((size_t)(jg * 16 + w * 2) * 32) * 512 + lane * 8;
      const uint16_t* qsp = Qs + lane * 8;
#pragma unroll 2
      for (int kb = 0; kb < 32; ++kb) {
        bf16x8 qf0 = *(const bf16x8*)(qsp + kb * 512);
        bf16x8 qf1 = *(const bf16x8*)(qsp + (32 + kb) * 512);
        bf16x8 kf0 = *(const bf16x8*)(kbp + (size_t)kb * 512);
        bf16x8 kf1 = *(const bf16x8*)(kbp + (size_t)(32 + kb) * 512);
        sacc[0][0] = MFMA16(qf0, kf0, sacc[0][0]);
        sacc[1][0] = MFMA16(qf1, kf0, sacc[1][0]);
        sacc[0][1] = MFMA16(qf0, kf1, sacc[0][1]);
        sacc[1][1] = MFMA16(qf1, kf1, sacc[1][1]);
      }

      // ---- causal mask (last tile only) ----------------------------------
      if (jg == jn - 1) {
#pragma unroll
        for (int mt = 0; mt < 2; ++mt)
#pragma unroll
          for (int nt = 0; nt < 2; ++nt)
#pragma unroll
            for (int r = 0; r < 4; ++r) {
              int col = jg * 256 + w * 32 + nt * 16 + lm;
              int row = row0 + mt * 16 + qd * 4 + r;
              if (col > row) sacc[mt][nt][r] = -1e30f;
            }
      }

      // ---- wave-local row max -> stats -----------------------------------
#pragma unroll
      for (int mt = 0; mt < 2; ++mt)
#pragma unroll
        for (int r = 0; r < 4; ++r) {
          float v = fmaxf(sacc[mt][0][r], sacc[mt][1][r]);
          v = fmaxf(v, __shfl_xor(v, 1));
          v = fmaxf(v, __shfl_xor(v, 2));
          v = fmaxf(v, __shfl_xor(v, 4));
          v = fmaxf(v, __shfl_xor(v, 8));
          if (lm == 0) stats[mt * 16 + qd * 4 + r][w] = v;
        }
      __syncthreads();  // (1) also guarantees prior C-pass1 Pb reads done

      // ---- softmax in registers ------------------------------------------
      float alpha[2][4], psum[2][4];
      uint16_t pvh[2][2][4];
#pragma unroll
      for (int mt = 0; mt < 2; ++mt)
#pragma unroll
        for (int r = 0; r < 4; ++r) {
          int rl = mt * 16 + qd * 4 + r;
          float4 g0 = *(const float4*)&stats[rl][0];
          float4 g1 = *(const float4*)&stats[rl][4];
          float gm = fmaxf(fmaxf(fmaxf(g0.x, g0.y), fmaxf(g0.z, g0.w)),
                           fmaxf(fmaxf(g1.x, g1.y), fmaxf(g1.z, g1.w)));
          float mn = fmaxf(m_run[mt][r], gm);
          alpha[mt][r] = exp2f((m_run[mt][r] - mn) * c1);
          m_run[mt][r] = mn;
          psum[mt][r] = 0.0f;
        }
#pragma unroll
      for (int mt = 0; mt < 2; ++mt)
#pragma unroll
        for (int nt = 0; nt < 2; ++nt)
#pragma unroll
          for (int r = 0; r < 4; ++r) {
            float pv = exp2f((sacc[mt][nt][r] - m_run[mt][r]) * c1);
            psum[mt][r] += pv;
            pvh[mt][nt][r] = f2bf(pv);
          }
#pragma unroll
      for (int mt = 0; mt < 2; ++mt)
#pragma unroll
        for (int r = 0; r < 4; ++r) {
          float s2 = psum[mt][r];
          s2 += __shfl_xor(s2, 1);
          s2 += __shfl_xor(s2, 2);
          s2 += __shfl_xor(s2, 4);
          s2 += __shfl_xor(s2, 8);
          l_run[mt][r] = l_run[mt][r] * alpha[mt][r] + s2;
        }
      if (wp == 0) {
#pragma unroll
        for (int mt = 0; mt < 2; ++mt)
#pragma unroll
          for (int nt = 0; nt < 2; ++nt)
#pragma unroll
            for (int r = 0; r < 4; ++r)
              Pb[((mt * 4 + wk) * 64 + (nt * 2 + (lm >> 3)) * 16 + qd * 4 + r) * 8 +
                 (lm & 7)] = pvh[mt][nt][r];
      }
      __syncthreads();  // (2) Pb pass-0 ready

      // ---- rescale O -----------------------------------------------------
#pragma unroll
      for (int mt = 0; mt < 2; ++mt)
#pragma unroll
        for (int dt = 0; dt < 8; ++dt)
#pragma unroll
          for (int r = 0; r < 4; ++r)
            o_acc[mt][dt][r] *= alpha[mt][r];

      // ---- C-pass 0: keys [jg*256, +128) ---------------------------------
      const uint16_t* vbp = Vblk + ((size_t)(w * 8) * 256 + jg * 8) * 512 + lane * 8;
#pragma unroll 2
      for (int kc = 0; kc < 4; ++kc) {
        bf16x8 pf0 = *(const bf16x8*)(Pb + (kc * 64 + lane) * 8);
        bf16x8 pf1 = *(const bf16x8*)(Pb + ((4 + kc) * 64 + lane) * 8);
#pragma unroll
        for (int dt = 0; dt < 8; ++dt) {
          bf16x8 vf = *(const bf16x8*)(vbp + ((size_t)dt * 256 + kc) * 512);
          o_acc[0][dt] = MFMA16(pf0, vf, o_acc[0][dt]);
          o_acc[1][dt] = MFMA16(pf1, vf, o_acc[1][dt]);
        }
      }
      __syncthreads();  // (3) Pb pass-0 consumed
      if (wp == 1) {
#pragma unroll
        for (int mt = 0; mt < 2; ++mt)
#pragma unroll
          for (int nt = 0; nt < 2; ++nt)
#pragma unroll
            for (int r = 0; r < 4; ++r)
              Pb[((mt * 4 + wk) * 64 + (nt * 2 + (lm >> 3)) * 16 + qd * 4 + r) * 8 +
                 (lm & 7)] = pvh[mt][nt][r];
      }
      __syncthreads();  // (4) Pb pass-1 ready

      // ---- C-pass 1: keys [jg*256+128, +128) -----------------------------
#pragma unroll 2
      for (int kc = 0; kc < 4; ++kc) {
        bf16x8 pf0 = *(const bf16x8*)(Pb + (kc * 64 + lane) * 8);
        bf16x8 pf1 = *(const bf16x8*)(Pb + ((4 + kc) * 64 + lane) * 8);
#pragma unroll
        for (int dt = 0; dt < 8; ++dt) {
          bf16x8 vf = *(const bf16x8*)(vbp + ((size_t)dt * 256 + 4 + kc) * 512);
          o_acc[0][dt] = MFMA16(pf0, vf, o_acc[0][dt]);
          o_acc[1][dt] = MFMA16(pf1, vf, o_acc[1][dt]);
        }
      }
      // next iter's stats write is fine (stats != Pb); Pb reuse gated by (1)
    }

    // ---- epilogue: stats (reused as lsum) + unnormalized partial O -------
    if (lm == 0) {
#pragma unroll
      for (int mt = 0; mt < 2; ++mt)
#pragma unroll
        for (int r = 0; r < 4; ++r) {
          int rl = mt * 16 + qd * 4 + r;
          stats[rl][w] = l_run[mt][r];
          if (w == 0) mrow[rl] = m_run[mt][r];
        }
    }
    __syncthreads();
    if (t < 32) {
      float4 a0 = *(const float4*)&stats[t][0];
      float4 a1 = *(const float4*)&stats[t][4];
      Mm[par * SEQ + row0 + t] = mrow[t];
      Ll[par * SEQ + row0 + t] = (a0.x + a0.y + a0.z + a0.w) + (a1.x + a1.y + a1.z + a1.w);
    }
    uint16_t* Pp = par ? P1 : P0;
#pragma unroll
    for (int mt = 0; mt < 2; ++mt)
#pragma unroll
      for (int dt = 0; dt < 8; ++dt)
#pragma unroll
        for (int r = 0; r < 4; ++r) {
          int row = row0 + mt * 16 + qd * 4 + r;
          int d   = w * 128 + dt * 16 + lm;
          Pp[(size_t)row * DIM + d] = f2bf(o_acc[mt][dt][r]);
        }
  }
}

// ------------------------------------------------------------ merge partials
__global__ __launch_bounds__(256) void merge_kernel(const uint16_t* __restrict__ P0,
                                                    const uint16_t* __restrict__ P1,
                                                    const float* __restrict__ Mm,
                                                    const float* __restrict__ Ll,
                                                    float* __restrict__ out) {
  const int row = blockIdx.x;
  const int d0  = threadIdx.x * 4;
  const float c1 = 0.045084220027780106f;
  float m0 = Mm[row], m1 = Mm[SEQ + row];
  float l0 = Ll[row], l1 = Ll[SEQ + row];
  float m  = fmaxf(m0, m1);
  float a0 = exp2f((m0 - m) * c1);
  float a1 = exp2f((m1 - m) * c1);
  float inv = 1.0f / (a0 * l0 + a1 * l1);
  ushort4 p0 = *(const ushort4*)(P0 + (size_t)row * DIM + d0);
  ushort4 p1 = *(const ushort4*)(P1 + (size_t)row * DIM + d0);
  float4 o;
  o.x = (a0 * bf2f(p0.x) + a1 * bf2f(p1.x)) * inv;
  o.y = (a0 * bf2f(p0.y) + a1 * bf2f(p1.y)) * inv;
  o.z = (a0 * bf2f(p0.z) + a1 * bf2f(p1.z)) * inv;
  o.w = (a0 * bf2f(p0.w) + a1 * bf2f(p1.w)) * inv;
  *(float4*)(out + (size_t)row * DIM + d0) = o;
}

// ---------------------------------------------------------------- launch
extern "C" void kernel_launch(void* const* d_in, const int* in_sizes, int n_in,
                              void* d_out, int out_size, void* d_ws, size_t ws_size,
                              hipStream_t stream) {
  (void)in_sizes; (void)n_in; (void)out_size; (void)ws_size;
  const float* x  = (const float*)d_in[0];
  const float* wq = (const float*)d_in[1];
  const float* wk = (const float*)d_in[2];
  const float* wv = (const float*)d_in[3];
  float* out = (float*)d_out;

  char* ws = (char*)d_ws;
  uint16_t* Qblk = (uint16_t*)(ws);                  // 16MB blocked
  uint16_t* Kblk = (uint16_t*)(ws + 16777216);       // 16MB blocked
  uint16_t* Vblk = (uint16_t*)(ws + 33554432);       // 16MB blocked
  uint16_t* Vb   = (uint16_t*)(ws + 50331648);       // 16MB row-major V
  uint16_t* P0   = (uint16_t*)(ws + 50331648);       // aliases Vb (dead after transpose)
  uint16_t* xb   = (uint16_t*)(ws + 67108864);       // 16MB
  uint16_t* P1   = (uint16_t*)(ws + 67108864);       // aliases xb (dead after GEMM)
  uint16_t* wcat = (uint16_t*)(ws + 83886080);       // 6MB
  float*    Mm   = (float*)(ws + 83886080);          // aliases wcat (dead after GEMM)
  float*    Ll   = (float*)(ws + 83886080 + 65536);

  cast_f32_bf16<<<8192, 256, 0, stream>>>(x,  xb,                   SEQ * DIM);
  cast_f32_bf16<<<1024, 256, 0, stream>>>(wq, wcat,                 DIM * DIM);
  cast_f32_bf16<<<1024, 256, 0, stream>>>(wk, wcat + DIM * DIM,     DIM * DIM);
  cast_f32_bf16<<<1024, 256, 0, stream>>>(wv, wcat + 2 * DIM * DIM, DIM * DIM);

  qkv_gemm<<<dim3(24, 64), 256, 0, stream>>>(xb, wcat, Qblk, Kblk, Vb);
  transpose_v<<<dim3(SEQ / 64, DIM / 64), 256, 0, stream>>>(Vb, Vblk);
  attn_kernel<<<256, 512, 0, stream>>>(Qblk, Kblk, Vblk, P0, P1, Mm, Ll);
  merge_kernel<<<SEQ, 256, 0, stream>>>(P0, P1, Mm, Ll, out);
}

// Round 6
// 535.245 us; speedup vs baseline: 1.7908x; 1.7908x over previous
//
#include <hip/hip_runtime.h>
#include <stdint.h>
#include <stddef.h>

// S=8192, D=1024 causal attention + QKV proj.
// fused cast->bf16, QKV MFMA GEMM (async LDS staging; writes Q/K/V in blocked
// MFMA-fragment layouts), flash attention (Br=32, Bc=256, 8 waves, pair-balanced
// grid + key-parity split-2, deep register pipelines for K/V streams), merge.

#define SEQ   8192
#define DIM   1024

typedef __bf16 bf16x8 __attribute__((ext_vector_type(8)));
typedef float  f32x4  __attribute__((ext_vector_type(4)));

#define MFMA16(a, b, c) __builtin_amdgcn_mfma_f32_16x16x32_bf16((a), (b), (c), 0, 0, 0)

__device__ __forceinline__ uint16_t f2bf(float f) {
  uint32_t u = __builtin_bit_cast(uint32_t, f);
  return (uint16_t)((u + 0x7fffu + ((u >> 16) & 1u)) >> 16);
}
__device__ __forceinline__ float bf2f(uint16_t h) {
  uint32_t u = ((uint32_t)h) << 16;
  return __builtin_bit_cast(float, u);
}

typedef const __attribute__((address_space(1))) uint32_t* gas_t;
typedef __attribute__((address_space(3))) uint32_t* las_t;
__device__ __forceinline__ void async16(const void* g, void* l) {
  __builtin_amdgcn_global_load_lds((gas_t)g, (las_t)l, 16, 0, 0);
}

// ------------------------------------------------------- fused cast kernel
__global__ __launch_bounds__(256) void cast_all(const float* __restrict__ x,
                                                const float* __restrict__ wq,
                                                const float* __restrict__ wk,
                                                const float* __restrict__ wv,
                                                uint16_t* __restrict__ xb,
                                                uint16_t* __restrict__ wcat) {
  int b = blockIdx.x;
  const float* src;
  uint16_t* dst;
  int i;
  if (b < 8192) {
    src = x; dst = xb; i = (b * 256 + threadIdx.x) * 4;
  } else {
    int wb = b - 8192;
    int sel = wb >> 10;
    src = sel == 0 ? wq : (sel == 1 ? wk : wv);
    dst = wcat + sel * 1048576;
    i = ((wb & 1023) * 256 + threadIdx.x) * 4;
  }
  float4 v = *(const float4*)(src + i);
  ushort4 o;
  o.x = f2bf(v.x); o.y = f2bf(v.y); o.z = f2bf(v.z); o.w = f2bf(v.w);
  *(ushort4*)(dst + i) = o;
}

// ------------------------------------------------------------- QKV GEMM
// async LDS staging (XOR-swizzled), 128x128 tile, BK=64.
// Epilogue scatters Q,K into blocked A/B-frag layout and V into blocked
// B-frag (d-major) layout directly (no separate transpose pass).
__global__ __launch_bounds__(256) void qkv_gemm(const uint16_t* __restrict__ A,
                                                const uint16_t* __restrict__ B,
                                                uint16_t* __restrict__ Qblk,
                                                uint16_t* __restrict__ Kblk,
                                                uint16_t* __restrict__ Vblk) {
  __shared__ __align__(16) uint16_t As[128 * 64];
  __shared__ __align__(16) uint16_t Bs[128 * 64];
  const int t    = threadIdx.x;
  const int w    = t >> 6;
  const int lane = t & 63;
  const int lm   = lane & 15;
  const int qd   = lane >> 4;
  const int wrow = (w >> 1) * 64;
  const int wcol = (w & 1) * 64;
  const int rowbase = blockIdx.y * 128;
  const int colbase = blockIdx.x * 128;

  const int lrow = lane >> 3;
  const int lgrp = (lane & 7) ^ (lrow & 7);

  f32x4 acc[4][4] = {};

  for (int kb = 0; kb < DIM; kb += 64) {
    __syncthreads();
#pragma unroll
    for (int rep = 0; rep < 4; ++rep) {
      int r0 = rep * 32 + w * 8;
      async16(A + (size_t)(rowbase + r0 + lrow) * DIM + kb + lgrp * 8, As + r0 * 64);
      async16(B + (size_t)(colbase + r0 + lrow) * DIM + kb + lgrp * 8, Bs + r0 * 64);
    }
    __syncthreads();
#pragma unroll
    for (int kc = 0; kc < 2; ++kc) {
      bf16x8 af[4], bfr[4];
#pragma unroll
      for (int mt = 0; mt < 4; ++mt) {
        int r = wrow + mt * 16 + lm;
        af[mt] = *(const bf16x8*)(As + r * 64 + (((kc * 4 + qd) ^ (lm & 7)) * 8));
      }
#pragma unroll
      for (int nt = 0; nt < 4; ++nt) {
        int r = wcol + nt * 16 + lm;
        bfr[nt] = *(const bf16x8*)(Bs + r * 64 + (((kc * 4 + qd) ^ (lm & 7)) * 8));
      }
#pragma unroll
      for (int mt = 0; mt < 4; ++mt)
#pragma unroll
        for (int nt = 0; nt < 4; ++nt)
          acc[mt][nt] = MFMA16(af[mt], bfr[nt], acc[mt][nt]);
    }
  }

#pragma unroll
  for (int mt = 0; mt < 4; ++mt)
#pragma unroll
    for (int nt = 0; nt < 4; ++nt)
#pragma unroll
      for (int r = 0; r < 4; ++r) {
        int m = rowbase + wrow + mt * 16 + qd * 4 + r;
        int n = colbase + wcol + nt * 16 + lm;
        uint16_t v = f2bf(acc[mt][nt][r]);
        int nn = n & 1023;
        if (n < 2048) {
          // Q/K A-frag layout: row=m, feat=nn
          size_t off = (((size_t)(m >> 4) * 32 + (nn >> 5)) * 64 +
                        ((nn >> 3) & 3) * 16 + (m & 15)) * 8 + (nn & 7);
          if (n < 1024) Qblk[off] = v; else Kblk[off] = v;
        } else {
          // V B-frag layout: key=m, d=nn
          size_t off = (((size_t)(nn >> 4) * 256 + (m >> 5)) * 64 +
                        ((m >> 3) & 3) * 16 + (nn & 15)) * 8 + (m & 7);
          Vblk[off] = v;
        }
      }
}

// ------------------------------------------------------------ flash attention
// Br=32 rows, Bc=256 keys/iter, 8 waves (512 thr), 2 waves/SIMD (<=256 regs).
// grid=256: pair p=b>>1 (halves tt=p, 255-p), parity par=b&1, jg=par,par+2,...
// Deep pipelines: phase A depth-8 K-fragment ring (16 loads in flight/wave);
// V kc=0,1 prefetched during softmax, depth-2 ring in phase C; next-iter K
// chunks 0..3 prefetched at phase C top.
__global__ __launch_bounds__(512, 2) void attn_kernel(const uint16_t* __restrict__ Qblk,
                                                      const uint16_t* __restrict__ Kblk,
                                                      const uint16_t* __restrict__ Vblk,
                                                      uint16_t* __restrict__ P0,
                                                      uint16_t* __restrict__ P1,
                                                      float* __restrict__ Mm,
                                                      float* __restrict__ Ll) {
  __shared__ __align__(16) uint16_t Qs[32768];   // 64KB blocked Q tile
  __shared__ __align__(16) uint16_t Pb[8192];    // 16KB P (A-frag blocked)
  __shared__ float stats[32][8];
  __shared__ float mrow[32];

  const int t    = threadIdx.x;
  const int w    = t >> 6;
  const int lane = t & 63;
  const int lm   = lane & 15;
  const int qd   = lane >> 4;
  const int par  = blockIdx.x & 1;
  const int p    = blockIdx.x >> 1;
  const float c1 = 0.045084220027780106f;  // log2(e)/sqrt(1024)

#pragma unroll 1
  for (int half = 0; half < 2; ++half) {
    const int tt   = half ? 255 - p : p;
    const int row0 = tt * 32;
    const int jn   = (tt >> 3) + 1;

    __syncthreads();  // previous half done with Qs
#pragma unroll
    for (int i = 0; i < 8; ++i)
      async16(Qblk + ((size_t)(tt * 64 + w * 8 + i)) * 512 + lane * 8,
              Qs + (w * 8 + i) * 512);

    // prime next-K prefetch for jg=par (drained by the barrier below)
    bf16x8 kpre0[4], kpre1[4];
    {
      const uint16_t* kbp0 = Kblk + ((size_t)(par * 16 + w * 2) * 32) * 512 + lane * 8;
#pragma unroll
      for (int c = 0; c < 4; ++c) {
        kpre0[c] = *(const bf16x8*)(kbp0 + (size_t)c * 512);
        kpre1[c] = *(const bf16x8*)(kbp0 + (size_t)(32 + c) * 512);
      }
    }
    __syncthreads();  // drain Qs DMA

    float m_run[2][4], l_run[2][4];
#pragma unroll
    for (int mt = 0; mt < 2; ++mt)
#pragma unroll
      for (int r = 0; r < 4; ++r) { m_run[mt][r] = -1e30f; l_run[mt][r] = 0.0f; }
    f32x4 o_acc[2][8] = {};

#pragma unroll 1
    for (int jg = par; jg < jn; jg += 2) {
      const uint16_t* kbp = Kblk + ((size_t)(jg * 16 + w * 2) * 32) * 512 + lane * 8;
      const uint16_t* vbp = Vblk + ((size_t)(w * 8) * 256 + jg * 8) * 512 + lane * 8;
      const uint16_t* qsp = Qs + lane * 8;

      // ---- Phase A: depth-8 rolling K ring -------------------------------
      f32x4 sacc[2][2] = {};
      bf16x8 kr0[8], kr1[8];
#pragma unroll
      for (int c = 0; c < 4; ++c) { kr0[c] = kpre0[c]; kr1[c] = kpre1[c]; }
#pragma unroll
      for (int c = 4; c < 8; ++c) {
        kr0[c] = *(const bf16x8*)(kbp + (size_t)c * 512);
        kr1[c] = *(const bf16x8*)(kbp + (size_t)(32 + c) * 512);
      }
#pragma unroll
      for (int kb = 0; kb < 32; ++kb) {
        bf16x8 q0 = *(const bf16x8*)(qsp + kb * 512);
        bf16x8 q1 = *(const bf16x8*)(qsp + (32 + kb) * 512);
        sacc[0][0] = MFMA16(q0, kr0[kb & 7], sacc[0][0]);
        sacc[1][0] = MFMA16(q1, kr0[kb & 7], sacc[1][0]);
        sacc[0][1] = MFMA16(q0, kr1[kb & 7], sacc[0][1]);
        sacc[1][1] = MFMA16(q1, kr1[kb & 7], sacc[1][1]);
        if (kb < 24) {
          kr0[kb & 7] = *(const bf16x8*)(kbp + (size_t)(kb + 8) * 512);
          kr1[kb & 7] = *(const bf16x8*)(kbp + (size_t)(32 + kb + 8) * 512);
        }
      }

      // ---- causal mask (diagonal tile only) ------------------------------
      if (jg == jn - 1) {
#pragma unroll
        for (int mt = 0; mt < 2; ++mt)
#pragma unroll
          for (int nt = 0; nt < 2; ++nt)
#pragma unroll
            for (int r = 0; r < 4; ++r) {
              int col = jg * 256 + w * 32 + nt * 16 + lm;
              int row = row0 + mt * 16 + qd * 4 + r;
              if (col > row) sacc[mt][nt][r] = -1e30f;
            }
      }

      // ---- wave-local row max -> stats -----------------------------------
#pragma unroll
      for (int mt = 0; mt < 2; ++mt)
#pragma unroll
        for (int r = 0; r < 4; ++r) {
          float v = fmaxf(sacc[mt][0][r], sacc[mt][1][r]);
          v = fmaxf(v, __shfl_xor(v, 1));
          v = fmaxf(v, __shfl_xor(v, 2));
          v = fmaxf(v, __shfl_xor(v, 4));
          v = fmaxf(v, __shfl_xor(v, 8));
          if (lm == 0) stats[mt * 16 + qd * 4 + r][w] = v;
        }
      __syncthreads();  // (1) stats ready; also gates Pb reuse

      // ---- V prefetch kc=0,1 (flies during softmax) ----------------------
      bf16x8 vr0[8], vr1[8];
#pragma unroll
      for (int dt = 0; dt < 8; ++dt) {
        vr0[dt] = *(const bf16x8*)(vbp + ((size_t)dt * 256 + 0) * 512);
        vr1[dt] = *(const bf16x8*)(vbp + ((size_t)dt * 256 + 1) * 512);
      }

      // ---- softmax in registers; P (blocked) to LDS ----------------------
      float alpha[2][4], psum[2][4];
#pragma unroll
      for (int mt = 0; mt < 2; ++mt)
#pragma unroll
        for (int r = 0; r < 4; ++r) {
          int rl = mt * 16 + qd * 4 + r;
          float4 g0 = *(const float4*)&stats[rl][0];
          float4 g1 = *(const float4*)&stats[rl][4];
          float gm = fmaxf(fmaxf(fmaxf(g0.x, g0.y), fmaxf(g0.z, g0.w)),
                           fmaxf(fmaxf(g1.x, g1.y), fmaxf(g1.z, g1.w)));
          float mn = fmaxf(m_run[mt][r], gm);
          alpha[mt][r] = exp2f((m_run[mt][r] - mn) * c1);
          m_run[mt][r] = mn;
          psum[mt][r] = 0.0f;
        }
#pragma unroll
      for (int mt = 0; mt < 2; ++mt)
#pragma unroll
        for (int nt = 0; nt < 2; ++nt)
#pragma unroll
          for (int r = 0; r < 4; ++r) {
            float pv = exp2f((sacc[mt][nt][r] - m_run[mt][r]) * c1);
            psum[mt][r] += pv;
            Pb[((mt * 8 + w) * 64 + (nt * 2 + (lm >> 3)) * 16 + qd * 4 + r) * 8 +
               (lm & 7)] = f2bf(pv);
          }
#pragma unroll
      for (int mt = 0; mt < 2; ++mt)
#pragma unroll
        for (int r = 0; r < 4; ++r) {
          float s2 = psum[mt][r];
          s2 += __shfl_xor(s2, 1);
          s2 += __shfl_xor(s2, 2);
          s2 += __shfl_xor(s2, 4);
          s2 += __shfl_xor(s2, 8);
          l_run[mt][r] = l_run[mt][r] * alpha[mt][r] + s2;
        }
      __syncthreads();  // (2) Pb ready

      // ---- next-iter K prefetch (lands during phase C) -------------------
      {
        const uint16_t* kbpn = Kblk + ((size_t)((jg + 2) * 16 + w * 2) * 32) * 512 + lane * 8;
#pragma unroll
        for (int c = 0; c < 4; ++c) {
          kpre0[c] = *(const bf16x8*)(kbpn + (size_t)c * 512);
          kpre1[c] = *(const bf16x8*)(kbpn + (size_t)(32 + c) * 512);
        }
      }

      // ---- rescale O -----------------------------------------------------
#pragma unroll
      for (int mt = 0; mt < 2; ++mt)
#pragma unroll
        for (int dt = 0; dt < 8; ++dt)
#pragma unroll
          for (int r = 0; r < 4; ++r)
            o_acc[mt][dt][r] *= alpha[mt][r];

      // ---- Phase C: O += P @ V, depth-2 V ring ---------------------------
#pragma unroll
      for (int kc = 0; kc < 8; ++kc) {
        bf16x8 pf0 = *(const bf16x8*)(Pb + (kc * 64 + lane) * 8);
        bf16x8 pf1 = *(const bf16x8*)(Pb + ((8 + kc) * 64 + lane) * 8);
#pragma unroll
        for (int dt = 0; dt < 8; ++dt) {
          bf16x8 vf = (kc & 1) ? vr1[dt] : vr0[dt];
          o_acc[0][dt] = MFMA16(pf0, vf, o_acc[0][dt]);
          o_acc[1][dt] = MFMA16(pf1, vf, o_acc[1][dt]);
        }
        if (kc < 6) {
#pragma unroll
          for (int dt = 0; dt < 8; ++dt) {
            if (kc & 1)
              vr1[dt] = *(const bf16x8*)(vbp + ((size_t)dt * 256 + kc + 2) * 512);
            else
              vr0[dt] = *(const bf16x8*)(vbp + ((size_t)dt * 256 + kc + 2) * 512);
          }
        }
      }
    }

    // ---- epilogue: stats (reused as lsum) + unnormalized partial O -------
    if (lm == 0) {
#pragma unroll
      for (int mt = 0; mt < 2; ++mt)
#pragma unroll
        for (int r = 0; r < 4; ++r) {
          int rl = mt * 16 + qd * 4 + r;
          stats[rl][w] = l_run[mt][r];
          if (w == 0) mrow[rl] = m_run[mt][r];
        }
    }
    __syncthreads();
    if (t < 32) {
      float4 a0 = *(const float4*)&stats[t][0];
      float4 a1 = *(const float4*)&stats[t][4];
      Mm[par * SEQ + row0 + t] = mrow[t];
      Ll[par * SEQ + row0 + t] = (a0.x + a0.y + a0.z + a0.w) + (a1.x + a1.y + a1.z + a1.w);
    }
    uint16_t* Pp = par ? P1 : P0;
#pragma unroll
    for (int mt = 0; mt < 2; ++mt)
#pragma unroll
      for (int dt = 0; dt < 8; ++dt)
#pragma unroll
        for (int r = 0; r < 4; ++r) {
          int row = row0 + mt * 16 + qd * 4 + r;
          int d   = w * 128 + dt * 16 + lm;
          Pp[(size_t)row * DIM + d] = f2bf(o_acc[mt][dt][r]);
        }
  }
}

// ------------------------------------------------------------ merge partials
__global__ __launch_bounds__(256) void merge_kernel(const uint16_t* __restrict__ P0,
                                                    const uint16_t* __restrict__ P1,
                                                    const float* __restrict__ Mm,
                                                    const float* __restrict__ Ll,
                                                    float* __restrict__ out) {
  const int row = blockIdx.x;
  const int d0  = threadIdx.x * 4;
  const float c1 = 0.045084220027780106f;
  float m0 = Mm[row], m1 = Mm[SEQ + row];
  float l0 = Ll[row], l1 = Ll[SEQ + row];
  float m  = fmaxf(m0, m1);
  float a0 = exp2f((m0 - m) * c1);
  float a1 = exp2f((m1 - m) * c1);
  float inv = 1.0f / (a0 * l0 + a1 * l1);
  ushort4 p0 = *(const ushort4*)(P0 + (size_t)row * DIM + d0);
  ushort4 p1 = *(const ushort4*)(P1 + (size_t)row * DIM + d0);
  float4 o;
  o.x = (a0 * bf2f(p0.x) + a1 * bf2f(p1.x)) * inv;
  o.y = (a0 * bf2f(p0.y) + a1 * bf2f(p1.y)) * inv;
  o.z = (a0 * bf2f(p0.z) + a1 * bf2f(p1.z)) * inv;
  o.w = (a0 * bf2f(p0.w) + a1 * bf2f(p1.w)) * inv;
  *(float4*)(out + (size_t)row * DIM + d0) = o;
}

// ---------------------------------------------------------------- launch
extern "C" void kernel_launch(void* const* d_in, const int* in_sizes, int n_in,
                              void* d_out, int out_size, void* d_ws, size_t ws_size,
                              hipStream_t stream) {
  (void)in_sizes; (void)n_in; (void)out_size; (void)ws_size;
  const float* x  = (const float*)d_in[0];
  const float* wq = (const float*)d_in[1];
  const float* wk = (const float*)d_in[2];
  const float* wv = (const float*)d_in[3];
  float* out = (float*)d_out;

  char* ws = (char*)d_ws;
  uint16_t* Qblk = (uint16_t*)(ws);                  // 16MB blocked
  uint16_t* Kblk = (uint16_t*)(ws + 16777216);       // 16MB blocked
  uint16_t* Vblk = (uint16_t*)(ws + 33554432);       // 16MB blocked
  uint16_t* P0   = (uint16_t*)(ws + 50331648);       // 16MB partial 0
  uint16_t* xb   = (uint16_t*)(ws + 67108864);       // 16MB
  uint16_t* P1   = (uint16_t*)(ws + 67108864);       // aliases xb (dead after GEMM)
  uint16_t* wcat = (uint16_t*)(ws + 83886080);       // 6MB
  float*    Mm   = (float*)(ws + 83886080);          // aliases wcat (dead after GEMM)
  float*    Ll   = (float*)(ws + 83886080 + 65536);

  cast_all<<<11264, 256, 0, stream>>>(x, wq, wk, wv, xb, wcat);
  qkv_gemm<<<dim3(24, 64), 256, 0, stream>>>(xb, wcat, Qblk, Kblk, Vblk);
  attn_kernel<<<256, 512, 0, stream>>>(Qblk, Kblk, Vblk, P0, P1, Mm, Ll);
  merge_kernel<<<SEQ, 256, 0, stream>>>(P0, P1, Mm, Ll, out);
}